// Round 5
// baseline (353.876 us; speedup 1.0000x reference)
//
#include <hip/hip_runtime.h>

#define B_  2
#define T_  1024
#define D_  2048
#define NH  16
#define KH  4
#define HD  128
#define TC_ 1024
#define S_  2048

typedef __bf16 bf16x4v __attribute__((ext_vector_type(4)));
typedef __bf16 bf16x8v __attribute__((ext_vector_type(8)));
typedef float  f32x4v  __attribute__((ext_vector_type(4)));

__device__ __forceinline__ void async_copy16(void* lds, const void* g) {
    __builtin_amdgcn_global_load_lds(
        (__attribute__((address_space(1))) void*)g,
        (__attribute__((address_space(3))) void*)lds, 16, 0, 0);
}

// ---------------- x fp32 -> bf16 ----------------
__global__ void cvt_x(const float* __restrict__ x, __bf16* __restrict__ xb) {
    int i = (blockIdx.x * 256 + threadIdx.x) * 4;
    float4 v = *(const float4*)(x + i);
    bf16x4v o; o[0]=(__bf16)v.x; o[1]=(__bf16)v.y; o[2]=(__bf16)v.z; o[3]=(__bf16)v.w;
    *(bf16x4v*)(xb + i) = o;
}

// ---------------- weight transposes ----------------
__global__ void tp_w(const float* __restrict__ in, __bf16* __restrict__ out) {
    __shared__ float tile[32][33];
    int h0 = blockIdx.x * 32;
    int d0 = blockIdx.y * 32;
    const float* ip = in + (size_t)blockIdx.z * (D_ * HD);
    __bf16* op = out + (size_t)blockIdx.z * (D_ * HD);
    int tx = threadIdx.x, ty = threadIdx.y;
    for (int i = 0; i < 32; i += 8)
        tile[ty + i][tx] = ip[(size_t)(d0 + ty + i) * HD + h0 + tx];
    __syncthreads();
    for (int i = 0; i < 32; i += 8)
        op[(size_t)(h0 + ty + i) * D_ + d0 + tx] = (__bf16)tile[tx][ty + i];
}

__global__ void tp_wout(const float* __restrict__ in, __bf16* __restrict__ out) {
    __shared__ float tile[32][33];
    int d0 = blockIdx.x * 32;
    int h0 = blockIdx.y * 32;
    int n  = blockIdx.z;
    const float* ip = in + (size_t)n * (HD * D_);
    int tx = threadIdx.x, ty = threadIdx.y;
    for (int i = 0; i < 32; i += 8)
        tile[ty + i][tx] = ip[(size_t)(h0 + ty + i) * D_ + d0 + tx];
    __syncthreads();
    for (int i = 0; i < 32; i += 8)
        out[(size_t)(d0 + ty + i) * (NH * HD) + n * HD + h0 + tx] = (__bf16)tile[tx][ty + i];
}

// v out region fp32 [B][S][K][H] -> vtb bf16 [B][K][H][S]
__global__ void tp_v(const float* __restrict__ vout, __bf16* __restrict__ vtb) {
    __shared__ float tile[32][33];
    int z = blockIdx.z; int b = z / KH, kh = z % KH;
    int h0 = blockIdx.x * 32;
    int s0 = blockIdx.y * 32;
    const float* ip = vout + ((size_t)b * S_ * KH + kh) * HD;
    int tx = threadIdx.x, ty = threadIdx.y;
    for (int i = 0; i < 32; i += 8)
        tile[ty + i][tx] = ip[(size_t)(s0 + ty + i) * (KH * HD) + h0 + tx];
    __syncthreads();
    __bf16* op = vtb + ((size_t)b * KH + kh) * (size_t)HD * S_;
    for (int i = 0; i < 32; i += 8)
        op[(size_t)(h0 + ty + i) * S_ + s0 + tx] = (__bf16)tile[tx][ty + i];
}

// ---------------- cache copy (fp32 exact) + bf16 K-cache ----------------
__global__ void copy_cache(const float4* __restrict__ ck, const float4* __restrict__ cv,
                           float* __restrict__ kout, float* __restrict__ vout,
                           __bf16* __restrict__ kb) {
    int i = blockIdx.x * 256 + threadIdx.x;     // 262144 total
    int b = i >> 17;
    int r = i & 131071;
    float4 kv = ck[i];
    ((float4*)(kout + (size_t)b * S_ * KH * HD))[r] = kv;
    ((float4*)(vout + (size_t)b * S_ * KH * HD))[r] = cv[i];
    int h4 = r & 31;
    int kh = (r >> 5) & 3;
    int s  = r >> 7;
    bf16x4v o; o[0]=(__bf16)kv.x; o[1]=(__bf16)kv.y; o[2]=(__bf16)kv.z; o[3]=(__bf16)kv.w;
    *(bf16x4v*)(kb + (((size_t)(b * KH + kh) * S_ + s) * HD) + h4 * 4) = o;
}

// ---------------- 128x128-tile bf16 GEMM, C = A @ BT^T, K=2048, swizzled LDS ----------------
__global__ __launch_bounds__(256, 2)
void gemm_bt(const __bf16* __restrict__ A, const __bf16* __restrict__ BT,
             float* __restrict__ C, int ldc) {
    __shared__ __bf16 As[128 * 64];
    __shared__ __bf16 Bs[128 * 64];
    const int m0 = blockIdx.x * 128, n0 = blockIdx.y * 128;
    const int tid = threadIdx.x;
    const int wave = tid >> 6, lane = tid & 63;
    const int quad = lane >> 4, l16 = lane & 15;
    const int wm = (wave & 1) * 64, wn = (wave >> 1) * 64;
    const int lrow = lane >> 3;
    const int lsw  = (lane & 7) ^ (lrow & 7);   // swizzled source chunk: slot(row,c) holds c^(row&7)

    f32x4v acc[4][4];
    for (int i = 0; i < 4; i++)
        for (int j = 0; j < 4; j++)
            acc[i][j] = (f32x4v){0.f, 0.f, 0.f, 0.f};

    const __bf16* Abase = A + (size_t)m0 * D_;
    const __bf16* Bbase = BT + (size_t)n0 * D_;

    for (int k0 = 0; k0 < D_; k0 += 64) {
        for (int j = 0; j < 4; j++) {
            int r = wave * 32 + j * 8;
            async_copy16(As + (size_t)r * 64,
                         Abase + (size_t)(r + lrow) * D_ + k0 + lsw * 8);
            async_copy16(Bs + (size_t)r * 64,
                         Bbase + (size_t)(r + lrow) * D_ + k0 + lsw * 8);
        }
        __syncthreads();
        for (int ks = 0; ks < 2; ks++) {
            const int ch = ((ks * 4 + quad) ^ (l16 & 7)) * 8;
            bf16x8v a[4], b[4];
            for (int i = 0; i < 4; i++)
                a[i] = *(const bf16x8v*)(As + (wm + i * 16 + l16) * 64 + ch);
            for (int j = 0; j < 4; j++)
                b[j] = *(const bf16x8v*)(Bs + (wn + j * 16 + l16) * 64 + ch);
            for (int i = 0; i < 4; i++)
                for (int j = 0; j < 4; j++)
                    acc[i][j] = __builtin_amdgcn_mfma_f32_16x16x32_bf16(a[i], b[j], acc[i][j], 0, 0, 0);
        }
        __syncthreads();
    }
    for (int i = 0; i < 4; i++)
        for (int j = 0; j < 4; j++)
            for (int r = 0; r < 4; r++) {
                int row = m0 + wm + i * 16 + quad * 4 + r;
                int col = n0 + wn + j * 16 + l16;
                C[(size_t)row * ldc + col] = acc[i][j][r];
            }
}

// ---------------- RoPE + scatter QKV (+ bf16 new-K) ----------------
__global__ void finish_rope(const float* __restrict__ proj, const int* __restrict__ pos,
                            __bf16* __restrict__ qws, float* __restrict__ kout,
                            float* __restrict__ vout, __bf16* __restrict__ kb) {
    const int tau = blockIdx.x;
    const int b = tau >> 10, t = tau & 1023;
    const float p = (float)pos[tau];
    const float* pr = proj + (size_t)tau * 3072;
    const float qscale = 0.08838834764831845f;   // 128^-0.5
    for (int idx = threadIdx.x; idx < (NH + KH) * 64; idx += 256) {
        int head = idx >> 6;
        int hh = idx & 63;
        float ang = p * __expf(-(float)hh * (9.210340371976184f / 64.0f));
        float sn, cs;
        __sincosf(ang, &sn, &cs);
        if (head < NH) {
            float x1 = pr[head * HD + hh], x2 = pr[head * HD + hh + 64];
            size_t qo = ((size_t)tau * NH + head) * HD;
            qws[qo + hh]      = (__bf16)((x1 * cs - x2 * sn) * qscale);
            qws[qo + hh + 64] = (__bf16)((x2 * cs + x1 * sn) * qscale);
        } else {
            int kh = head - NH;
            float x1 = pr[2048 + kh * HD + hh], x2 = pr[2048 + kh * HD + hh + 64];
            float k1 = x1 * cs - x2 * sn, k2 = x2 * cs + x1 * sn;
            size_t ko = ((size_t)(b * S_ + TC_ + t) * KH + kh) * HD;
            kout[ko + hh]      = k1;
            kout[ko + hh + 64] = k2;
            size_t kbo = ((size_t)(b * KH + kh) * S_ + TC_ + t) * HD;
            kb[kbo + hh]      = (__bf16)k1;
            kb[kbo + hh + 64] = (__bf16)k2;
        }
    }
    for (int idx = threadIdx.x; idx < KH * HD; idx += 256) {
        int kh = idx >> 7, h = idx & 127;
        vout[((size_t)(b * S_ + TC_ + t) * KH + kh) * HD + h] = pr[2560 + kh * HD + h];
    }
}

// ---------------- flash attention, split-S partial pass ----------------
// 8 waves x 32 q-rows (2 A-frags) = 256-row Q-tile; S-tile = 128.
// B-operand LDS reads are SHARED across the 2 A-frags in the ks loop ->
// per-output LDS-read traffic halves vs the 16-row/wave structure (the
// measured bottleneck: ~512KB ds_read per tile at ~85 B/cyc/CU).
// split-S=2 keeps grid at 256 blocks (1/CU); partials merged by combine().
__global__ __launch_bounds__(512, 2)
void attn(const __bf16* __restrict__ qws, const __bf16* __restrict__ kb,
          const __bf16* __restrict__ vtb, float* __restrict__ o0,
          float* __restrict__ o1, float* __restrict__ ml) {
    __shared__ __bf16 Ks[128 * 128];
    __shared__ __bf16 Vs[128 * 128];
    __shared__ __bf16 Ps[256 * 128];

    const int t0 = blockIdx.x * 256;
    const int n  = blockIdx.y;
    const int z  = blockIdx.z;
    const int b  = z >> 1, sp = z & 1;
    const int kh = n / (NH / KH);
    const int tid = threadIdx.x, wave = tid >> 6, lane = tid & 63;
    const int quad = lane >> 4, l16 = lane & 15;
    const int wm = wave * 32;          // this wave's 32 q-rows
    const int sw = wave * 16;          // staging row group
    const int arow = lane >> 4;
    const int acol = lane & 15;

    const __bf16* kbase = kb  + ((size_t)(b * KH + kh)) * S_ * HD;
    const __bf16* vbase = vtb + ((size_t)(b * KH + kh)) * (size_t)HD * S_;

    // Q A-fragments in registers: f in {0,1}, row = t0+wm+f*16+l16, chunk ks*4+quad
    bf16x8v qreg[2][4];
#pragma unroll
    for (int f = 0; f < 2; f++) {
        const __bf16* qrow = qws + ((size_t)(b * T_ + t0 + wm + f * 16 + l16) * NH + n) * HD;
#pragma unroll
        for (int ks = 0; ks < 4; ks++)
            qreg[f][ks] = *(const bf16x8v*)(qrow + (ks * 4 + quad) * 8);
    }

    // K tile [128 s][128 h], swizzled source chunk c^(row&15)
    auto stageK = [&](int s0) {
        const __bf16* ktile = kbase + (size_t)s0 * HD;
        for (int jj = 0; jj < 4; jj++) {
            int r0 = sw + jj * 4;
            int row = r0 + arow;
            async_copy16(Ks + (size_t)r0 * 128,
                         ktile + (size_t)row * HD + ((acol ^ (row & 15)) * 8));
        }
    };
    // V tile [128 h][128 s], swizzled source chunk c^(row&15)
    auto stageV = [&](int s0) {
        const __bf16* vtile = vbase + s0;
        for (int jj = 0; jj < 4; jj++) {
            int r0 = sw + jj * 4;
            int row = r0 + arow;
            async_copy16(Vs + (size_t)r0 * 128,
                         vtile + (size_t)row * S_ + ((acol ^ (row & 15)) * 8));
        }
    };

    float m_run[2][4], l_run[2][4];
    f32x4v o_acc[2][8];
#pragma unroll
    for (int f = 0; f < 2; f++)
        for (int r = 0; r < 4; r++) { m_run[f][r] = -INFINITY; l_run[f][r] = 0.f; }
#pragma unroll
    for (int f = 0; f < 2; f++)
        for (int j = 0; j < 8; j++) o_acc[f][j] = (f32x4v){0.f, 0.f, 0.f, 0.f};

    const int nTot = (TC_ + t0 + 256) >> 7;    // 10/12/14/16 (always even)
    const int half = nTot >> 1;
    const int stB = sp ? half : 0;
    const int stE = sp ? nTot : half;

    for (int st = stB; st < stE; st++) {
        const int s0 = st * 128;
        stageK(s0);
        stageV(s0);
        __syncthreads();

        // QK^T: 32 rows x 128 cols; B-fragments shared across both A-frags
        f32x4v sc[2][8];
#pragma unroll
        for (int f = 0; f < 2; f++)
            for (int j = 0; j < 8; j++) sc[f][j] = (f32x4v){0.f, 0.f, 0.f, 0.f};
#pragma unroll
        for (int ks = 0; ks < 4; ks++) {
            int ch = (ks * 4 + quad) ^ l16;
            bf16x8v bb[8];
#pragma unroll
            for (int j = 0; j < 8; j++)
                bb[j] = *(const bf16x8v*)(Ks + (j * 16 + l16) * 128 + ch * 8);
#pragma unroll
            for (int f = 0; f < 2; f++)
#pragma unroll
                for (int j = 0; j < 8; j++)
                    sc[f][j] = __builtin_amdgcn_mfma_f32_16x16x32_bf16(qreg[f][ks], bb[j], sc[f][j], 0, 0, 0);
        }

        // causal mask: last two S-tiles straddle the diagonal band
        if (st >= nTot - 2) {
#pragma unroll
            for (int f = 0; f < 2; f++)
                for (int j = 0; j < 8; j++)
                    for (int r = 0; r < 4; r++) {
                        int row = t0 + wm + f * 16 + quad * 4 + r;
                        int col = s0 + j * 16 + l16;
                        if (col > TC_ + row) sc[f][j][r] = -3.0e38f;
                    }
        }

        // online softmax (per fragment f), then P -> LDS
#pragma unroll
        for (int f = 0; f < 2; f++) {
            for (int r = 0; r < 4; r++) {
                float mx = sc[f][0][r];
                for (int j = 1; j < 8; j++) mx = fmaxf(mx, sc[f][j][r]);
                for (int off = 8; off >= 1; off >>= 1) mx = fmaxf(mx, __shfl_xor(mx, off, 64));
                mx = fmaxf(mx, m_run[f][r]);
                float alpha = __expf(m_run[f][r] - mx);
                m_run[f][r] = mx;
                float s = 0.f;
                for (int j = 0; j < 8; j++) {
                    float pv = __expf(sc[f][j][r] - mx);
                    sc[f][j][r] = pv;
                    s += pv;
                }
                for (int off = 8; off >= 1; off >>= 1) s += __shfl_xor(s, off, 64);
                l_run[f][r] = l_run[f][r] * alpha + s;
                for (int j = 0; j < 8; j++) o_acc[f][j][r] *= alpha;
            }
            for (int j = 0; j < 8; j++)
                for (int r = 0; r < 4; r++) {
                    int row = wm + f * 16 + quad * 4 + r;
                    int c = (j * 2 + (l16 >> 3)) ^ (row & 15);
                    Ps[row * 128 + c * 8 + (l16 & 7)] = (__bf16)sc[f][j][r];
                }
        }
        __syncthreads();

        // PV: o_acc += P(256x128) @ V(128x128); V B-frags shared across f
#pragma unroll
        for (int ks = 0; ks < 4; ks++) {
            int ch = (ks * 4 + quad) ^ l16;
            bf16x8v a0 = *(const bf16x8v*)(Ps + (wm + l16) * 128 + ch * 8);
            bf16x8v a1 = *(const bf16x8v*)(Ps + (wm + 16 + l16) * 128 + ch * 8);
            bf16x8v bb[8];
#pragma unroll
            for (int j = 0; j < 8; j++)
                bb[j] = *(const bf16x8v*)(Vs + (j * 16 + l16) * 128 + ch * 8);
#pragma unroll
            for (int j = 0; j < 8; j++) {
                o_acc[0][j] = __builtin_amdgcn_mfma_f32_16x16x32_bf16(a0, bb[j], o_acc[0][j], 0, 0, 0);
                o_acc[1][j] = __builtin_amdgcn_mfma_f32_16x16x32_bf16(a1, bb[j], o_acc[1][j], 0, 0, 0);
            }
        }
        __syncthreads();
    }

    // epilogue: unnormalized partial o (f32) + (m, l) per row
    float* op = sp ? o1 : o0;
#pragma unroll
    for (int f = 0; f < 2; f++)
        for (int r = 0; r < 4; r++) {
            int t = t0 + wm + f * 16 + quad * 4 + r;
            size_t rowi = ((size_t)(b * T_ + t) * NH + n);
            float* orow = op + rowi * HD;
            for (int j = 0; j < 8; j++)
                orow[j * 16 + l16] = o_acc[f][j][r];
            if (l16 == 0) {
                size_t mli = ((size_t)sp * (B_ * T_ * NH) + rowi) * 2;
                ml[mli]     = m_run[f][r];
                ml[mli + 1] = l_run[f][r];
            }
        }
}

// ---------------- combine the two split-S partials ----------------
__global__ void combine(const float* __restrict__ o0, const float* __restrict__ o1,
                        const float* __restrict__ ml, __bf16* __restrict__ enc) {
    int i = blockIdx.x * 256 + threadIdx.x;     // 1048576 = 32768 rows x 32 quads
    int row = i >> 5, q = i & 31;
    float m0 = ml[(size_t)row * 2], l0 = ml[(size_t)row * 2 + 1];
    float m1 = ml[((size_t)(B_ * T_ * NH) + row) * 2], l1 = ml[((size_t)(B_ * T_ * NH) + row) * 2 + 1];
    float m = fmaxf(m0, m1);
    float a0 = __expf(m0 - m), a1 = __expf(m1 - m);
    float inv = 1.f / (l0 * a0 + l1 * a1);
    f32x4v v0 = *(const f32x4v*)(o0 + (size_t)row * HD + q * 4);
    f32x4v v1 = *(const f32x4v*)(o1 + (size_t)row * HD + q * 4);
    bf16x4v o;
    for (int k = 0; k < 4; k++)
        o[k] = (__bf16)((v0[k] * a0 + v1[k] * a1) * inv);
    *(bf16x4v*)(enc + (size_t)row * HD + q * 4) = o;
}

extern "C" void kernel_launch(void* const* d_in, const int* in_sizes, int n_in,
                              void* d_out, int out_size, void* d_ws, size_t ws_size,
                              hipStream_t stream) {
    const float* x       = (const float*)d_in[0];
    const int*   pos     = (const int*)d_in[1];
    const float* cache_k = (const float*)d_in[3];
    const float* cache_v = (const float*)d_in[4];
    const float* w_q     = (const float*)d_in[5];
    const float* w_kv    = (const float*)d_in[6];
    const float* w_out   = (const float*)d_in[7];

    float* out  = (float*)d_out;
    float* kout = out  + (size_t)B_ * T_ * D_;
    float* vout = kout + (size_t)B_ * S_ * KH * HD;

    char* ws = (char*)d_ws;
    __bf16* xb   = (__bf16*)ws;  ws += (size_t)B_ * T_ * D_ * 2;
    __bf16* wt   = (__bf16*)ws;  ws += (size_t)3072 * D_ * 2;
    __bf16* wot  = (__bf16*)ws;  ws += (size_t)D_ * NH * HD * 2;
    float*  proj = (float*)ws;   ws += (size_t)B_ * T_ * 3072 * 4;
    __bf16* qws  = (__bf16*)ws;  ws += (size_t)B_ * T_ * NH * HD * 2;
    __bf16* kbuf = (__bf16*)ws;  ws += (size_t)B_ * S_ * KH * HD * 2;
    __bf16* vtb  = (__bf16*)ws;  ws += (size_t)B_ * S_ * KH * HD * 2;
    __bf16* enc  = (__bf16*)ws;  ws += (size_t)B_ * T_ * NH * HD * 2;
    float*  o1p  = (float*)ws;   ws += (size_t)B_ * T_ * NH * HD * 4;   // split1 partial
    float*  mlp  = (float*)ws;   ws += (size_t)2 * B_ * T_ * NH * 2 * 4;
    float*  o0p  = proj;   // proj (24MB) is dead after finish_rope; reuse 16MB

    cvt_x<<<4096, 256, 0, stream>>>(x, xb);
    tp_w<<<dim3(4, 64, 16), dim3(32, 8), 0, stream>>>(w_q, wt);
    tp_w<<<dim3(4, 64, 8),  dim3(32, 8), 0, stream>>>(w_kv, wt + (size_t)16 * HD * D_);
    tp_wout<<<dim3(64, 4, 16), dim3(32, 8), 0, stream>>>(w_out, wot);
    copy_cache<<<1024, 256, 0, stream>>>((const float4*)cache_k, (const float4*)cache_v, kout, vout, kbuf);
    gemm_bt<<<dim3(16, 24), 256, 0, stream>>>(xb, wt, proj, 3072);
    finish_rope<<<2048, 256, 0, stream>>>(proj, pos, qws, kout, vout, kbuf);
    tp_v<<<dim3(4, 64, 8), dim3(32, 8), 0, stream>>>(vout, vtb);
    attn<<<dim3(4, 16, 4), 512, 0, stream>>>(qws, kbuf, vtb, o0p, o1p, mlp);
    combine<<<4096, 256, 0, stream>>>(o0p, o1p, mlp, enc);
    gemm_bt<<<dim3(16, 16), 256, 0, stream>>>(enc, wot, out, 2048);
}

// Round 6
// 280.039 us; speedup vs baseline: 1.2637x; 1.2637x over previous
//
#include <hip/hip_runtime.h>

#define B_  2
#define T_  1024
#define D_  2048
#define NH  16
#define KH  4
#define HD  128
#define TC_ 1024
#define S_  2048

typedef __bf16 bf16x4v __attribute__((ext_vector_type(4)));
typedef __bf16 bf16x8v __attribute__((ext_vector_type(8)));
typedef float  f32x4v  __attribute__((ext_vector_type(4)));

__device__ __forceinline__ void async_copy16(void* lds, const void* g) {
    __builtin_amdgcn_global_load_lds(
        (__attribute__((address_space(1))) void*)g,
        (__attribute__((address_space(3))) void*)lds, 16, 0, 0);
}

// ---------------- x fp32 -> bf16 ----------------
__global__ void cvt_x(const float* __restrict__ x, __bf16* __restrict__ xb) {
    int i = (blockIdx.x * 256 + threadIdx.x) * 4;
    float4 v = *(const float4*)(x + i);
    bf16x4v o; o[0]=(__bf16)v.x; o[1]=(__bf16)v.y; o[2]=(__bf16)v.z; o[3]=(__bf16)v.w;
    *(bf16x4v*)(xb + i) = o;
}

// ---------------- weight transposes ----------------
__global__ void tp_w(const float* __restrict__ in, __bf16* __restrict__ out) {
    __shared__ float tile[32][33];
    int h0 = blockIdx.x * 32;
    int d0 = blockIdx.y * 32;
    const float* ip = in + (size_t)blockIdx.z * (D_ * HD);
    __bf16* op = out + (size_t)blockIdx.z * (D_ * HD);
    int tx = threadIdx.x, ty = threadIdx.y;
    for (int i = 0; i < 32; i += 8)
        tile[ty + i][tx] = ip[(size_t)(d0 + ty + i) * HD + h0 + tx];
    __syncthreads();
    for (int i = 0; i < 32; i += 8)
        op[(size_t)(h0 + ty + i) * D_ + d0 + tx] = (__bf16)tile[tx][ty + i];
}

__global__ void tp_wout(const float* __restrict__ in, __bf16* __restrict__ out) {
    __shared__ float tile[32][33];
    int d0 = blockIdx.x * 32;
    int h0 = blockIdx.y * 32;
    int n  = blockIdx.z;
    const float* ip = in + (size_t)n * (HD * D_);
    int tx = threadIdx.x, ty = threadIdx.y;
    for (int i = 0; i < 32; i += 8)
        tile[ty + i][tx] = ip[(size_t)(h0 + ty + i) * D_ + d0 + tx];
    __syncthreads();
    for (int i = 0; i < 32; i += 8)
        out[(size_t)(d0 + ty + i) * (NH * HD) + n * HD + h0 + tx] = (__bf16)tile[tx][ty + i];
}

// v out region fp32 [B][S][K][H] -> vtb bf16 [B][K][H][S]
__global__ void tp_v(const float* __restrict__ vout, __bf16* __restrict__ vtb) {
    __shared__ float tile[32][33];
    int z = blockIdx.z; int b = z / KH, kh = z % KH;
    int h0 = blockIdx.x * 32;
    int s0 = blockIdx.y * 32;
    const float* ip = vout + ((size_t)b * S_ * KH + kh) * HD;
    int tx = threadIdx.x, ty = threadIdx.y;
    for (int i = 0; i < 32; i += 8)
        tile[ty + i][tx] = ip[(size_t)(s0 + ty + i) * (KH * HD) + h0 + tx];
    __syncthreads();
    __bf16* op = vtb + ((size_t)b * KH + kh) * (size_t)HD * S_;
    for (int i = 0; i < 32; i += 8)
        op[(size_t)(h0 + ty + i) * S_ + s0 + tx] = (__bf16)tile[tx][ty + i];
}

// ---------------- cache copy (fp32 exact) + bf16 K-cache ----------------
__global__ void copy_cache(const float4* __restrict__ ck, const float4* __restrict__ cv,
                           float* __restrict__ kout, float* __restrict__ vout,
                           __bf16* __restrict__ kb) {
    int i = blockIdx.x * 256 + threadIdx.x;     // 262144 total
    int b = i >> 17;
    int r = i & 131071;
    float4 kv = ck[i];
    ((float4*)(kout + (size_t)b * S_ * KH * HD))[r] = kv;
    ((float4*)(vout + (size_t)b * S_ * KH * HD))[r] = cv[i];
    int h4 = r & 31;
    int kh = (r >> 5) & 3;
    int s  = r >> 7;
    bf16x4v o; o[0]=(__bf16)kv.x; o[1]=(__bf16)kv.y; o[2]=(__bf16)kv.z; o[3]=(__bf16)kv.w;
    *(bf16x4v*)(kb + (((size_t)(b * KH + kh) * S_ + s) * HD) + h4 * 4) = o;
}

// ---------------- 128x128-tile bf16 GEMM, C = A @ BT^T, split-K via blockIdx.z ----
// blockIdx.z selects K-range [z*kchunk, (z+1)*kchunk) and output buffer (C0/C1).
// Split-K doubles blocks/CU so co-resident blocks hide each other's barrier
// drains (m102 shape penalty at 1 block/CU; m114 wave-level overlap).
__global__ __launch_bounds__(256, 2)
void gemm_bt(const __bf16* __restrict__ A, const __bf16* __restrict__ BT,
             float* __restrict__ C0, float* __restrict__ C1, int ldc, int kchunk) {
    __shared__ __bf16 As[128 * 64];
    __shared__ __bf16 Bs[128 * 64];
    const int m0 = blockIdx.x * 128, n0 = blockIdx.y * 128;
    const int kbeg = blockIdx.z * kchunk;
    float* C = blockIdx.z ? C1 : C0;
    const int tid = threadIdx.x;
    const int wave = tid >> 6, lane = tid & 63;
    const int quad = lane >> 4, l16 = lane & 15;
    const int wm = (wave & 1) * 64, wn = (wave >> 1) * 64;
    const int lrow = lane >> 3;
    const int lsw  = (lane & 7) ^ (lrow & 7);   // swizzled source chunk: slot(row,c) holds c^(row&7)

    f32x4v acc[4][4];
    for (int i = 0; i < 4; i++)
        for (int j = 0; j < 4; j++)
            acc[i][j] = (f32x4v){0.f, 0.f, 0.f, 0.f};

    const __bf16* Abase = A + (size_t)m0 * D_;
    const __bf16* Bbase = BT + (size_t)n0 * D_;

    for (int k0 = kbeg; k0 < kbeg + kchunk; k0 += 64) {
        for (int j = 0; j < 4; j++) {
            int r = wave * 32 + j * 8;
            async_copy16(As + (size_t)r * 64,
                         Abase + (size_t)(r + lrow) * D_ + k0 + lsw * 8);
            async_copy16(Bs + (size_t)r * 64,
                         Bbase + (size_t)(r + lrow) * D_ + k0 + lsw * 8);
        }
        __syncthreads();
        for (int ks = 0; ks < 2; ks++) {
            const int ch = ((ks * 4 + quad) ^ (l16 & 7)) * 8;
            bf16x8v a[4], b[4];
            for (int i = 0; i < 4; i++)
                a[i] = *(const bf16x8v*)(As + (wm + i * 16 + l16) * 64 + ch);
            for (int j = 0; j < 4; j++)
                b[j] = *(const bf16x8v*)(Bs + (wn + j * 16 + l16) * 64 + ch);
            for (int i = 0; i < 4; i++)
                for (int j = 0; j < 4; j++)
                    acc[i][j] = __builtin_amdgcn_mfma_f32_16x16x32_bf16(a[i], b[j], acc[i][j], 0, 0, 0);
        }
        __syncthreads();
    }
    for (int i = 0; i < 4; i++)
        for (int j = 0; j < 4; j++)
            for (int r = 0; r < 4; r++) {
                int row = m0 + wm + i * 16 + quad * 4 + r;
                int col = n0 + wn + j * 16 + l16;
                C[(size_t)row * ldc + col] = acc[i][j][r];
            }
}

// ---------------- add the two split-K partials of the output GEMM ----------------
__global__ void add2(float* __restrict__ out, const float* __restrict__ p1) {
    int i = blockIdx.x * 256 + threadIdx.x;
    f32x4v a = *(const f32x4v*)(out + (size_t)i * 4);
    f32x4v b = *(const f32x4v*)(p1 + (size_t)i * 4);
    a[0]+=b[0]; a[1]+=b[1]; a[2]+=b[2]; a[3]+=b[3];
    *(f32x4v*)(out + (size_t)i * 4) = a;
}

// ---------------- RoPE + scatter QKV (+ bf16 new-K); sums split-K partials ------
__global__ void finish_rope(const float* __restrict__ proj, const int* __restrict__ pos,
                            __bf16* __restrict__ qws, float* __restrict__ kout,
                            float* __restrict__ vout, __bf16* __restrict__ kb) {
    const int tau = blockIdx.x;
    const int b = tau >> 10, t = tau & 1023;
    const float p = (float)pos[tau];
    const float* pr  = proj + (size_t)tau * 3072;
    const float* pr2 = pr + (size_t)2048 * 3072;    // split-K partial 1
    const float qscale = 0.08838834764831845f;   // 128^-0.5
    for (int idx = threadIdx.x; idx < (NH + KH) * 64; idx += 256) {
        int head = idx >> 6;
        int hh = idx & 63;
        float ang = p * __expf(-(float)hh * (9.210340371976184f / 64.0f));
        float sn, cs;
        __sincosf(ang, &sn, &cs);
        if (head < NH) {
            float x1 = pr[head * HD + hh]      + pr2[head * HD + hh];
            float x2 = pr[head * HD + hh + 64] + pr2[head * HD + hh + 64];
            size_t qo = ((size_t)tau * NH + head) * HD;
            qws[qo + hh]      = (__bf16)((x1 * cs - x2 * sn) * qscale);
            qws[qo + hh + 64] = (__bf16)((x2 * cs + x1 * sn) * qscale);
        } else {
            int kh = head - NH;
            float x1 = pr[2048 + kh * HD + hh]      + pr2[2048 + kh * HD + hh];
            float x2 = pr[2048 + kh * HD + hh + 64] + pr2[2048 + kh * HD + hh + 64];
            float k1 = x1 * cs - x2 * sn, k2 = x2 * cs + x1 * sn;
            size_t ko = ((size_t)(b * S_ + TC_ + t) * KH + kh) * HD;
            kout[ko + hh]      = k1;
            kout[ko + hh + 64] = k2;
            size_t kbo = ((size_t)(b * KH + kh) * S_ + TC_ + t) * HD;
            kb[kbo + hh]      = (__bf16)k1;
            kb[kbo + hh + 64] = (__bf16)k2;
        }
    }
    for (int idx = threadIdx.x; idx < KH * HD; idx += 256) {
        int kh = idx >> 7, h = idx & 127;
        vout[((size_t)(b * S_ + TC_ + t) * KH + kh) * HD + h] =
            pr[2560 + kh * HD + h] + pr2[2560 + kh * HD + h];
    }
}

// ---------------- flash attention (8 waves, XOR-swizzled LDS) — round-1 proven ----
__global__ __launch_bounds__(512, 1)
void attn(const __bf16* __restrict__ qws, const __bf16* __restrict__ kb,
          const __bf16* __restrict__ vtb, __bf16* __restrict__ enc) {
    __shared__ __bf16 Qs[128 * 128];
    __shared__ __bf16 Ks[128 * 128];
    __shared__ __bf16 Vs[128 * 128];
    __shared__ __bf16 Ps[128 * 128];

    const int t0 = blockIdx.x * 128;
    const int n  = blockIdx.y;
    const int b  = blockIdx.z;
    const int kh = n / (NH / KH);
    const int tid = threadIdx.x, wave = tid >> 6, lane = tid & 63;
    const int quad = lane >> 4, l16 = lane & 15;
    const int wm = wave * 16;
    const int arow = lane >> 4;
    const int acol = lane & 15;

    // Q tile [128 t][128 h], swizzled source
    {
        const __bf16* qtile = qws + ((size_t)(b * T_ + t0) * NH + n) * HD;
        for (int jj = 0; jj < 4; jj++) {
            int r0 = wm + jj * 4;
            int row = r0 + arow;
            async_copy16(Qs + (size_t)r0 * 128,
                         qtile + (size_t)row * (NH * HD) + ((acol ^ (row & 15)) * 8));
        }
    }

    float m_run[4], l_run[4];
    f32x4v o_acc[8];
    for (int r = 0; r < 4; r++) { m_run[r] = -INFINITY; l_run[r] = 0.f; }
    for (int j = 0; j < 8; j++) o_acc[j] = (f32x4v){0.f, 0.f, 0.f, 0.f};

    const int nS = (TC_ + t0 + 128) >> 7;
    const __bf16* kbase = kb  + ((size_t)(b * KH + kh)) * S_ * HD;
    const __bf16* vbase = vtb + ((size_t)(b * KH + kh)) * (size_t)HD * S_;

    for (int st = 0; st < nS; st++) {
        const int s0 = st * 128;
        {
            const __bf16* ktile = kbase + (size_t)s0 * HD;
            for (int jj = 0; jj < 4; jj++) {
                int r0 = wm + jj * 4;
                int row = r0 + arow;
                async_copy16(Ks + (size_t)r0 * 128,
                             ktile + (size_t)row * HD + ((acol ^ (row & 15)) * 8));
            }
        }
        {
            const __bf16* vtile = vbase + s0;
            for (int jj = 0; jj < 4; jj++) {
                int r0 = wm + jj * 4;
                int row = r0 + arow;
                async_copy16(Vs + (size_t)r0 * 128,
                             vtile + (size_t)row * S_ + ((acol ^ (row & 15)) * 8));
            }
        }
        __syncthreads();

        // QK^T: this wave's 16 rows x 128 cols
        f32x4v sc[8];
        for (int j = 0; j < 8; j++) sc[j] = (f32x4v){0.f, 0.f, 0.f, 0.f};
        for (int ks = 0; ks < 4; ks++) {
            int ch = (ks * 4 + quad) ^ l16;
            bf16x8v a = *(const bf16x8v*)(Qs + (wm + l16) * 128 + ch * 8);
            bf16x8v bb[8];
            for (int j = 0; j < 8; j++)
                bb[j] = *(const bf16x8v*)(Ks + (j * 16 + l16) * 128 + ch * 8);
            for (int j = 0; j < 8; j++)
                sc[j] = __builtin_amdgcn_mfma_f32_16x16x32_bf16(a, bb[j], sc[j], 0, 0, 0);
        }

        // causal mask (diagonal tile only: s0 == TC + t0)
        if (st == nS - 1) {
            for (int j = 0; j < 8; j++)
                for (int r = 0; r < 4; r++) {
                    int row = wm + quad * 4 + r;
                    int col = j * 16 + l16;
                    if (col > row) sc[j][r] = -3.0e38f;
                }
        }

        // online softmax
        for (int r = 0; r < 4; r++) {
            float mx = sc[0][r];
            for (int j = 1; j < 8; j++) mx = fmaxf(mx, sc[j][r]);
            for (int off = 8; off >= 1; off >>= 1) mx = fmaxf(mx, __shfl_xor(mx, off, 64));
            mx = fmaxf(mx, m_run[r]);
            float alpha = __expf(m_run[r] - mx);
            m_run[r] = mx;
            float s = 0.f;
            for (int j = 0; j < 8; j++) {
                float pv = __expf(sc[j][r] - mx);
                sc[j][r] = pv;
                s += pv;
            }
            for (int off = 8; off >= 1; off >>= 1) s += __shfl_xor(s, off, 64);
            l_run[r] = l_run[r] * alpha + s;
            for (int j = 0; j < 8; j++) o_acc[j][r] *= alpha;
        }

        // P -> LDS (C-layout -> A-layout), swizzled chunks
        for (int j = 0; j < 8; j++)
            for (int r = 0; r < 4; r++) {
                int row = wm + quad * 4 + r;
                int c = (j * 2 + (l16 >> 3)) ^ (row & 15);
                Ps[row * 128 + c * 8 + (l16 & 7)] = (__bf16)sc[j][r];
            }
        __syncthreads();

        // PV: o_acc += P @ V
        for (int ks = 0; ks < 4; ks++) {
            int ch = (ks * 4 + quad) ^ l16;
            bf16x8v a = *(const bf16x8v*)(Ps + (wm + l16) * 128 + ch * 8);
            bf16x8v bb[8];
            for (int j = 0; j < 8; j++)
                bb[j] = *(const bf16x8v*)(Vs + (j * 16 + l16) * 128 + ch * 8);
            for (int j = 0; j < 8; j++)
                o_acc[j] = __builtin_amdgcn_mfma_f32_16x16x32_bf16(a, bb[j], o_acc[j], 0, 0, 0);
        }
        __syncthreads();
    }

    // epilogue: enc[b,t,n,h] bf16
    for (int r = 0; r < 4; r++) {
        float inv = 1.0f / l_run[r];
        int row = wm + quad * 4 + r;
        for (int j = 0; j < 8; j++) {
            int col = j * 16 + l16;
            enc[((size_t)(b * T_ + t0 + row) * NH + n) * HD + col] =
                (__bf16)(o_acc[j][r] * inv);
        }
    }
}

extern "C" void kernel_launch(void* const* d_in, const int* in_sizes, int n_in,
                              void* d_out, int out_size, void* d_ws, size_t ws_size,
                              hipStream_t stream) {
    const float* x       = (const float*)d_in[0];
    const int*   pos     = (const int*)d_in[1];
    const float* cache_k = (const float*)d_in[3];
    const float* cache_v = (const float*)d_in[4];
    const float* w_q     = (const float*)d_in[5];
    const float* w_kv    = (const float*)d_in[6];
    const float* w_out   = (const float*)d_in[7];

    float* out  = (float*)d_out;
    float* kout = out  + (size_t)B_ * T_ * D_;
    float* vout = kout + (size_t)B_ * S_ * KH * HD;

    char* ws = (char*)d_ws;
    __bf16* xb   = (__bf16*)ws;  ws += (size_t)B_ * T_ * D_ * 2;
    __bf16* wt   = (__bf16*)ws;  ws += (size_t)3072 * D_ * 2;
    __bf16* wot  = (__bf16*)ws;  ws += (size_t)D_ * NH * HD * 2;
    float*  proj = (float*)ws;   ws += (size_t)2 * B_ * T_ * 3072 * 4;   // 2x: split-K partials
    __bf16* qws  = (__bf16*)ws;  ws += (size_t)B_ * T_ * NH * HD * 2;
    __bf16* kbuf = (__bf16*)ws;  ws += (size_t)B_ * S_ * KH * HD * 2;
    __bf16* vtb  = (__bf16*)ws;  ws += (size_t)B_ * S_ * KH * HD * 2;
    __bf16* enc  = (__bf16*)ws;
    float*  proj1 = proj + (size_t)2048 * 3072;
    float*  op1   = proj;   // proj dead after finish_rope; reuse 16MB for gemm2 partial

    cvt_x<<<4096, 256, 0, stream>>>(x, xb);
    tp_w<<<dim3(4, 64, 16), dim3(32, 8), 0, stream>>>(w_q, wt);
    tp_w<<<dim3(4, 64, 8),  dim3(32, 8), 0, stream>>>(w_kv, wt + (size_t)16 * HD * D_);
    tp_wout<<<dim3(64, 4, 16), dim3(32, 8), 0, stream>>>(w_out, wot);
    copy_cache<<<1024, 256, 0, stream>>>((const float4*)cache_k, (const float4*)cache_v, kout, vout, kbuf);
    gemm_bt<<<dim3(16, 24, 2), 256, 0, stream>>>(xb, wt, proj, proj1, 3072, 1024);
    finish_rope<<<2048, 256, 0, stream>>>(proj, pos, qws, kout, vout, kbuf);
    tp_v<<<dim3(4, 64, 8), dim3(32, 8), 0, stream>>>(vout, vtb);
    attn<<<dim3(8, 16, 2), 512, 0, stream>>>(qws, kbuf, vtb, enc);
    gemm_bt<<<dim3(16, 16, 2), 256, 0, stream>>>(enc, wot, out, op1, 2048, 1024);
    add2<<<4096, 256, 0, stream>>>(out, op1);
}

// Round 7
// 274.424 us; speedup vs baseline: 1.2895x; 1.0205x over previous
//
#include <hip/hip_runtime.h>

#define B_  2
#define T_  1024
#define D_  2048
#define NH  16
#define KH  4
#define HD  128
#define TC_ 1024
#define S_  2048

typedef __bf16 bf16x4v __attribute__((ext_vector_type(4)));
typedef __bf16 bf16x8v __attribute__((ext_vector_type(8)));
typedef float  f32x4v  __attribute__((ext_vector_type(4)));

__device__ __forceinline__ void async_copy16(void* lds, const void* g) {
    __builtin_amdgcn_global_load_lds(
        (__attribute__((address_space(1))) void*)g,
        (__attribute__((address_space(3))) void*)lds, 16, 0, 0);
}

// ---------------- x fp32 -> bf16 ----------------
__global__ void cvt_x(const float* __restrict__ x, __bf16* __restrict__ xb) {
    int i = (blockIdx.x * 256 + threadIdx.x) * 4;
    float4 v = *(const float4*)(x + i);
    bf16x4v o; o[0]=(__bf16)v.x; o[1]=(__bf16)v.y; o[2]=(__bf16)v.z; o[3]=(__bf16)v.w;
    *(bf16x4v*)(xb + i) = o;
}

// ---------------- weight transposes ----------------
__global__ void tp_w(const float* __restrict__ in, __bf16* __restrict__ out) {
    __shared__ float tile[32][33];
    int h0 = blockIdx.x * 32;
    int d0 = blockIdx.y * 32;
    const float* ip = in + (size_t)blockIdx.z * (D_ * HD);
    __bf16* op = out + (size_t)blockIdx.z * (D_ * HD);
    int tx = threadIdx.x, ty = threadIdx.y;
    for (int i = 0; i < 32; i += 8)
        tile[ty + i][tx] = ip[(size_t)(d0 + ty + i) * HD + h0 + tx];
    __syncthreads();
    for (int i = 0; i < 32; i += 8)
        op[(size_t)(h0 + ty + i) * D_ + d0 + tx] = (__bf16)tile[tx][ty + i];
}

__global__ void tp_wout(const float* __restrict__ in, __bf16* __restrict__ out) {
    __shared__ float tile[32][33];
    int d0 = blockIdx.x * 32;
    int h0 = blockIdx.y * 32;
    int n  = blockIdx.z;
    const float* ip = in + (size_t)n * (HD * D_);
    int tx = threadIdx.x, ty = threadIdx.y;
    for (int i = 0; i < 32; i += 8)
        tile[ty + i][tx] = ip[(size_t)(h0 + ty + i) * D_ + d0 + tx];
    __syncthreads();
    for (int i = 0; i < 32; i += 8)
        out[(size_t)(d0 + ty + i) * (NH * HD) + n * HD + h0 + tx] = (__bf16)tile[tx][ty + i];
}

// v out region fp32 [B][S][K][H] -> vtb bf16 [B][K][H][S]
__global__ void tp_v(const float* __restrict__ vout, __bf16* __restrict__ vtb) {
    __shared__ float tile[32][33];
    int z = blockIdx.z; int b = z / KH, kh = z % KH;
    int h0 = blockIdx.x * 32;
    int s0 = blockIdx.y * 32;
    const float* ip = vout + ((size_t)b * S_ * KH + kh) * HD;
    int tx = threadIdx.x, ty = threadIdx.y;
    for (int i = 0; i < 32; i += 8)
        tile[ty + i][tx] = ip[(size_t)(s0 + ty + i) * (KH * HD) + h0 + tx];
    __syncthreads();
    __bf16* op = vtb + ((size_t)b * KH + kh) * (size_t)HD * S_;
    for (int i = 0; i < 32; i += 8)
        op[(size_t)(h0 + ty + i) * S_ + s0 + tx] = (__bf16)tile[tx][ty + i];
}

// ---------------- cache copy (fp32 exact) + bf16 K-cache ----------------
__global__ void copy_cache(const float4* __restrict__ ck, const float4* __restrict__ cv,
                           float* __restrict__ kout, float* __restrict__ vout,
                           __bf16* __restrict__ kb) {
    int i = blockIdx.x * 256 + threadIdx.x;     // 262144 total
    int b = i >> 17;
    int r = i & 131071;
    float4 kv = ck[i];
    ((float4*)(kout + (size_t)b * S_ * KH * HD))[r] = kv;
    ((float4*)(vout + (size_t)b * S_ * KH * HD))[r] = cv[i];
    int h4 = r & 31;
    int kh = (r >> 5) & 3;
    int s  = r >> 7;
    bf16x4v o; o[0]=(__bf16)kv.x; o[1]=(__bf16)kv.y; o[2]=(__bf16)kv.z; o[3]=(__bf16)kv.w;
    *(bf16x4v*)(kb + (((size_t)(b * KH + kh) * S_ + s) * HD) + h4 * 4) = o;
}

// ---------------- QKV GEMM with fused RoPE/scatter epilogue ----------------
// C = xb @ wt^T (K=2048, full), 128x128 tiles. Wave n-fragment slots remapped to
// n_j = (wave>>1)*32 + (j>>1)*16 + (j&1)*64 so RoPE pairs (h, h+64) sit in the
// same wave as acc[i][2p] / acc[i][2p+1]. Epilogue dispatches on blockIdx.y:
// y<16: Q head y -> qws (RoPE*scale, bf16)
// y<20: K head y-16 -> kout (f32) + kb (bf16), RoPE
// else: V head y-20 -> vout (f32)
__global__ __launch_bounds__(256, 2)
void gemm_qkv(const __bf16* __restrict__ A, const __bf16* __restrict__ BT,
              const int* __restrict__ pos, __bf16* __restrict__ qws,
              float* __restrict__ kout, float* __restrict__ vout,
              __bf16* __restrict__ kb) {
    __shared__ __bf16 As[128 * 64];
    __shared__ __bf16 Bs[128 * 64];
    const int m0 = blockIdx.x * 128, n0 = blockIdx.y * 128;
    const int tid = threadIdx.x;
    const int wave = tid >> 6, lane = tid & 63;
    const int quad = lane >> 4, l16 = lane & 15;
    const int wm = (wave & 1) * 64;
    const int bn0 = (wave >> 1) * 32;          // n-slot base for this wave
    const int lrow = lane >> 3;
    const int lsw  = (lane & 7) ^ (lrow & 7);

    f32x4v acc[4][4];
    for (int i = 0; i < 4; i++)
        for (int j = 0; j < 4; j++)
            acc[i][j] = (f32x4v){0.f, 0.f, 0.f, 0.f};

    const __bf16* Abase = A + (size_t)m0 * D_;
    const __bf16* Bbase = BT + (size_t)n0 * D_;

    for (int k0 = 0; k0 < D_; k0 += 64) {
        for (int j = 0; j < 4; j++) {
            int r = wave * 32 + j * 8;
            async_copy16(As + (size_t)r * 64,
                         Abase + (size_t)(r + lrow) * D_ + k0 + lsw * 8);
            async_copy16(Bs + (size_t)r * 64,
                         Bbase + (size_t)(r + lrow) * D_ + k0 + lsw * 8);
        }
        __syncthreads();
        for (int ks = 0; ks < 2; ks++) {
            const int ch = ((ks * 4 + quad) ^ (l16 & 7)) * 8;
            bf16x8v a[4], b[4];
            for (int i = 0; i < 4; i++)
                a[i] = *(const bf16x8v*)(As + (wm + i * 16 + l16) * 64 + ch);
            for (int j = 0; j < 4; j++) {
                int bn = bn0 + (j >> 1) * 16 + (j & 1) * 64;
                b[j] = *(const bf16x8v*)(Bs + (bn + l16) * 64 + ch);
            }
            for (int i = 0; i < 4; i++)
                for (int j = 0; j < 4; j++)
                    acc[i][j] = __builtin_amdgcn_mfma_f32_16x16x32_bf16(a[i], b[j], acc[i][j], 0, 0, 0);
        }
        __syncthreads();
    }

    const float RFREQ = 9.210340371976184f / 64.0f;   // ln(1e4)/64
    const float qscale = 0.08838834764831845f;        // 128^-0.5
    const int head = blockIdx.y;

    if (head < NH) {
        // ---- Q: RoPE * qscale -> qws bf16 [tau][NH][HD]
        for (int i = 0; i < 4; i++)
            for (int r = 0; r < 4; r++) {
                int row = m0 + wm + i * 16 + quad * 4 + r;
                float p = (float)pos[row];
                size_t qo = ((size_t)row * NH + head) * HD;
                for (int jp = 0; jp < 2; jp++) {
                    int hh = bn0 + jp * 16 + l16;
                    float ang = p * __expf(-(float)hh * RFREQ);
                    float sn, cs; __sincosf(ang, &sn, &cs);
                    float x1 = acc[i][jp * 2][r], x2 = acc[i][jp * 2 + 1][r];
                    qws[qo + hh]      = (__bf16)((x1 * cs - x2 * sn) * qscale);
                    qws[qo + hh + 64] = (__bf16)((x2 * cs + x1 * sn) * qscale);
                }
            }
    } else if (head < NH + KH) {
        // ---- K: RoPE -> kout f32 [b][s][kh][h] + kb bf16 [b][kh][s][h]
        int kh = head - NH;
        for (int i = 0; i < 4; i++)
            for (int r = 0; r < 4; r++) {
                int row = m0 + wm + i * 16 + quad * 4 + r;
                int b = row >> 10, t = row & 1023;
                float p = (float)pos[row];
                size_t ko  = ((size_t)(b * S_ + TC_ + t) * KH + kh) * HD;
                size_t kbo = ((size_t)(b * KH + kh) * S_ + TC_ + t) * HD;
                for (int jp = 0; jp < 2; jp++) {
                    int hh = bn0 + jp * 16 + l16;
                    float ang = p * __expf(-(float)hh * RFREQ);
                    float sn, cs; __sincosf(ang, &sn, &cs);
                    float x1 = acc[i][jp * 2][r], x2 = acc[i][jp * 2 + 1][r];
                    float k1 = x1 * cs - x2 * sn, k2 = x2 * cs + x1 * sn;
                    kout[ko + hh]      = k1;
                    kout[ko + hh + 64] = k2;
                    kb[kbo + hh]      = (__bf16)k1;
                    kb[kbo + hh + 64] = (__bf16)k2;
                }
            }
    } else {
        // ---- V: plain store -> vout f32 [b][s][kh][h]
        int kh = head - NH - KH;
        for (int i = 0; i < 4; i++)
            for (int r = 0; r < 4; r++) {
                int row = m0 + wm + i * 16 + quad * 4 + r;
                int b = row >> 10, t = row & 1023;
                size_t vo = ((size_t)(b * S_ + TC_ + t) * KH + kh) * HD;
                for (int j = 0; j < 4; j++) {
                    int h = bn0 + (j >> 1) * 16 + (j & 1) * 64 + l16;
                    vout[vo + h] = acc[i][j][r];
                }
            }
    }
}

// ---------------- 128x128-tile bf16 GEMM, C = A @ BT^T, split-K via blockIdx.z ----
__global__ __launch_bounds__(256, 2)
void gemm_bt(const __bf16* __restrict__ A, const __bf16* __restrict__ BT,
             float* __restrict__ C0, float* __restrict__ C1, int ldc, int kchunk) {
    __shared__ __bf16 As[128 * 64];
    __shared__ __bf16 Bs[128 * 64];
    const int m0 = blockIdx.x * 128, n0 = blockIdx.y * 128;
    const int kbeg = blockIdx.z * kchunk;
    float* C = blockIdx.z ? C1 : C0;
    const int tid = threadIdx.x;
    const int wave = tid >> 6, lane = tid & 63;
    const int quad = lane >> 4, l16 = lane & 15;
    const int wm = (wave & 1) * 64, wn = (wave >> 1) * 64;
    const int lrow = lane >> 3;
    const int lsw  = (lane & 7) ^ (lrow & 7);

    f32x4v acc[4][4];
    for (int i = 0; i < 4; i++)
        for (int j = 0; j < 4; j++)
            acc[i][j] = (f32x4v){0.f, 0.f, 0.f, 0.f};

    const __bf16* Abase = A + (size_t)m0 * D_;
    const __bf16* Bbase = BT + (size_t)n0 * D_;

    for (int k0 = kbeg; k0 < kbeg + kchunk; k0 += 64) {
        for (int j = 0; j < 4; j++) {
            int r = wave * 32 + j * 8;
            async_copy16(As + (size_t)r * 64,
                         Abase + (size_t)(r + lrow) * D_ + k0 + lsw * 8);
            async_copy16(Bs + (size_t)r * 64,
                         Bbase + (size_t)(r + lrow) * D_ + k0 + lsw * 8);
        }
        __syncthreads();
        for (int ks = 0; ks < 2; ks++) {
            const int ch = ((ks * 4 + quad) ^ (l16 & 7)) * 8;
            bf16x8v a[4], b[4];
            for (int i = 0; i < 4; i++)
                a[i] = *(const bf16x8v*)(As + (wm + i * 16 + l16) * 64 + ch);
            for (int j = 0; j < 4; j++)
                b[j] = *(const bf16x8v*)(Bs + (wn + j * 16 + l16) * 64 + ch);
            for (int i = 0; i < 4; i++)
                for (int j = 0; j < 4; j++)
                    acc[i][j] = __builtin_amdgcn_mfma_f32_16x16x32_bf16(a[i], b[j], acc[i][j], 0, 0, 0);
        }
        __syncthreads();
    }
    for (int i = 0; i < 4; i++)
        for (int j = 0; j < 4; j++)
            for (int r = 0; r < 4; r++) {
                int row = m0 + wm + i * 16 + quad * 4 + r;
                int col = n0 + wn + j * 16 + l16;
                C[(size_t)row * ldc + col] = acc[i][j][r];
            }
}

// ---------------- add the two split-K partials of the output GEMM ----------------
__global__ void add2(float* __restrict__ out, const float* __restrict__ p1) {
    int i = blockIdx.x * 256 + threadIdx.x;
    f32x4v a = *(const f32x4v*)(out + (size_t)i * 4);
    f32x4v b = *(const f32x4v*)(p1 + (size_t)i * 4);
    a[0]+=b[0]; a[1]+=b[1]; a[2]+=b[2]; a[3]+=b[3];
    *(f32x4v*)(out + (size_t)i * 4) = a;
}

// ---------------- flash attention (8 waves, XOR-swizzled LDS) — round-1 proven ----
__global__ __launch_bounds__(512, 1)
void attn(const __bf16* __restrict__ qws, const __bf16* __restrict__ kb,
          const __bf16* __restrict__ vtb, __bf16* __restrict__ enc) {
    __shared__ __bf16 Qs[128 * 128];
    __shared__ __bf16 Ks[128 * 128];
    __shared__ __bf16 Vs[128 * 128];
    __shared__ __bf16 Ps[128 * 128];

    const int t0 = blockIdx.x * 128;
    const int n  = blockIdx.y;
    const int b  = blockIdx.z;
    const int kh = n / (NH / KH);
    const int tid = threadIdx.x, wave = tid >> 6, lane = tid & 63;
    const int quad = lane >> 4, l16 = lane & 15;
    const int wm = wave * 16;
    const int arow = lane >> 4;
    const int acol = lane & 15;

    // Q tile [128 t][128 h], swizzled source
    {
        const __bf16* qtile = qws + ((size_t)(b * T_ + t0) * NH + n) * HD;
        for (int jj = 0; jj < 4; jj++) {
            int r0 = wm + jj * 4;
            int row = r0 + arow;
            async_copy16(Qs + (size_t)r0 * 128,
                         qtile + (size_t)row * (NH * HD) + ((acol ^ (row & 15)) * 8));
        }
    }

    float m_run[4], l_run[4];
    f32x4v o_acc[8];
    for (int r = 0; r < 4; r++) { m_run[r] = -INFINITY; l_run[r] = 0.f; }
    for (int j = 0; j < 8; j++) o_acc[j] = (f32x4v){0.f, 0.f, 0.f, 0.f};

    const int nS = (TC_ + t0 + 128) >> 7;
    const __bf16* kbase = kb  + ((size_t)(b * KH + kh)) * S_ * HD;
    const __bf16* vbase = vtb + ((size_t)(b * KH + kh)) * (size_t)HD * S_;

    for (int st = 0; st < nS; st++) {
        const int s0 = st * 128;
        {
            const __bf16* ktile = kbase + (size_t)s0 * HD;
            for (int jj = 0; jj < 4; jj++) {
                int r0 = wm + jj * 4;
                int row = r0 + arow;
                async_copy16(Ks + (size_t)r0 * 128,
                             ktile + (size_t)row * HD + ((acol ^ (row & 15)) * 8));
            }
        }
        {
            const __bf16* vtile = vbase + s0;
            for (int jj = 0; jj < 4; jj++) {
                int r0 = wm + jj * 4;
                int row = r0 + arow;
                async_copy16(Vs + (size_t)r0 * 128,
                             vtile + (size_t)row * S_ + ((acol ^ (row & 15)) * 8));
            }
        }
        __syncthreads();

        // QK^T: this wave's 16 rows x 128 cols
        f32x4v sc[8];
        for (int j = 0; j < 8; j++) sc[j] = (f32x4v){0.f, 0.f, 0.f, 0.f};
        for (int ks = 0; ks < 4; ks++) {
            int ch = (ks * 4 + quad) ^ l16;
            bf16x8v a = *(const bf16x8v*)(Qs + (wm + l16) * 128 + ch * 8);
            bf16x8v bb[8];
            for (int j = 0; j < 8; j++)
                bb[j] = *(const bf16x8v*)(Ks + (j * 16 + l16) * 128 + ch * 8);
            for (int j = 0; j < 8; j++)
                sc[j] = __builtin_amdgcn_mfma_f32_16x16x32_bf16(a, bb[j], sc[j], 0, 0, 0);
        }

        // causal mask (diagonal tile only: s0 == TC + t0)
        if (st == nS - 1) {
            for (int j = 0; j < 8; j++)
                for (int r = 0; r < 4; r++) {
                    int row = wm + quad * 4 + r;
                    int col = j * 16 + l16;
                    if (col > row) sc[j][r] = -3.0e38f;
                }
        }

        // online softmax
        for (int r = 0; r < 4; r++) {
            float mx = sc[0][r];
            for (int j = 1; j < 8; j++) mx = fmaxf(mx, sc[j][r]);
            for (int off = 8; off >= 1; off >>= 1) mx = fmaxf(mx, __shfl_xor(mx, off, 64));
            mx = fmaxf(mx, m_run[r]);
            float alpha = __expf(m_run[r] - mx);
            m_run[r] = mx;
            float s = 0.f;
            for (int j = 0; j < 8; j++) {
                float pv = __expf(sc[j][r] - mx);
                sc[j][r] = pv;
                s += pv;
            }
            for (int off = 8; off >= 1; off >>= 1) s += __shfl_xor(s, off, 64);
            l_run[r] = l_run[r] * alpha + s;
            for (int j = 0; j < 8; j++) o_acc[j][r] *= alpha;
        }

        // P -> LDS (C-layout -> A-layout), swizzled chunks
        for (int j = 0; j < 8; j++)
            for (int r = 0; r < 4; r++) {
                int row = wm + quad * 4 + r;
                int c = (j * 2 + (l16 >> 3)) ^ (row & 15);
                Ps[row * 128 + c * 8 + (l16 & 7)] = (__bf16)sc[j][r];
            }
        __syncthreads();

        // PV: o_acc += P @ V
        for (int ks = 0; ks < 4; ks++) {
            int ch = (ks * 4 + quad) ^ l16;
            bf16x8v a = *(const bf16x8v*)(Ps + (wm + l16) * 128 + ch * 8);
            bf16x8v bb[8];
            for (int j = 0; j < 8; j++)
                bb[j] = *(const bf16x8v*)(Vs + (j * 16 + l16) * 128 + ch * 8);
            for (int j = 0; j < 8; j++)
                o_acc[j] = __builtin_amdgcn_mfma_f32_16x16x32_bf16(a, bb[j], o_acc[j], 0, 0, 0);
        }
        __syncthreads();
    }

    // epilogue: enc[b,t,n,h] bf16
    for (int r = 0; r < 4; r++) {
        float inv = 1.0f / l_run[r];
        int row = wm + quad * 4 + r;
        for (int j = 0; j < 8; j++) {
            int col = j * 16 + l16;
            enc[((size_t)(b * T_ + t0 + row) * NH + n) * HD + col] =
                (__bf16)(o_acc[j][r] * inv);
        }
    }
}

extern "C" void kernel_launch(void* const* d_in, const int* in_sizes, int n_in,
                              void* d_out, int out_size, void* d_ws, size_t ws_size,
                              hipStream_t stream) {
    const float* x       = (const float*)d_in[0];
    const int*   pos     = (const int*)d_in[1];
    const float* cache_k = (const float*)d_in[3];
    const float* cache_v = (const float*)d_in[4];
    const float* w_q     = (const float*)d_in[5];
    const float* w_kv    = (const float*)d_in[6];
    const float* w_out   = (const float*)d_in[7];

    float* out  = (float*)d_out;
    float* kout = out  + (size_t)B_ * T_ * D_;
    float* vout = kout + (size_t)B_ * S_ * KH * HD;

    char* ws = (char*)d_ws;
    __bf16* xb   = (__bf16*)ws;  ws += (size_t)B_ * T_ * D_ * 2;
    __bf16* wt   = (__bf16*)ws;  ws += (size_t)3072 * D_ * 2;
    __bf16* wot  = (__bf16*)ws;  ws += (size_t)D_ * NH * HD * 2;
    float*  op1  = (float*)ws;   ws += (size_t)B_ * T_ * D_ * 4;     // gemm2 split-K partial
    __bf16* qws  = (__bf16*)ws;  ws += (size_t)B_ * T_ * NH * HD * 2;
    __bf16* kbuf = (__bf16*)ws;  ws += (size_t)B_ * S_ * KH * HD * 2;
    __bf16* vtb  = (__bf16*)ws;  ws += (size_t)B_ * S_ * KH * HD * 2;
    __bf16* enc  = (__bf16*)ws;

    cvt_x<<<4096, 256, 0, stream>>>(x, xb);
    tp_w<<<dim3(4, 64, 16), dim3(32, 8), 0, stream>>>(w_q, wt);
    tp_w<<<dim3(4, 64, 8),  dim3(32, 8), 0, stream>>>(w_kv, wt + (size_t)16 * HD * D_);
    tp_wout<<<dim3(64, 4, 16), dim3(32, 8), 0, stream>>>(w_out, wot);
    copy_cache<<<1024, 256, 0, stream>>>((const float4*)cache_k, (const float4*)cache_v, kout, vout, kbuf);
    gemm_qkv<<<dim3(16, 24), 256, 0, stream>>>(xb, wt, pos, qws, kout, vout, kbuf);
    tp_v<<<dim3(4, 64, 8), dim3(32, 8), 0, stream>>>(vout, vtb);
    attn<<<dim3(8, 16, 2), 512, 0, stream>>>(qws, kbuf, vtb, enc);
    gemm_bt<<<dim3(16, 16, 2), 256, 0, stream>>>(enc, wot, out, op1, 2048, 1024);
    add2<<<4096, 256, 0, stream>>>(out, op1);
}